// Round 11
// baseline (453.969 us; speedup 1.0000x reference)
//
#include <hip/hip_runtime.h>
#include <cstdint>
#include <cstddef>

typedef float f32x4 __attribute__((ext_vector_type(4)));
typedef float f32x16 __attribute__((ext_vector_type(16)));
typedef short s16x8 __attribute__((ext_vector_type(8)));
typedef short s16x4 __attribute__((ext_vector_type(4)));

#define DEV static __device__ __forceinline__

DEV float bf2f(short s) {
  union { unsigned u; float f; } c;
  c.u = ((unsigned)(unsigned short)s) << 16;
  return c.f;
}
DEV short f2bf(float f) {
  union { float f; unsigned u; } c;
  c.f = f;
  unsigned r = c.u + 0x7fffu + ((c.u >> 16) & 1u);
  return (short)(r >> 16);
}
DEV float wave_allsum(float v) {
#pragma unroll
  for (int off = 32; off > 0; off >>= 1) v += __shfl_xor(v, off, 64);
  return v;
}
DEV void gload_lds16(const void* g, void* l) {
  __builtin_amdgcn_global_load_lds(
      (const __attribute__((address_space(1))) void*)g,
      (__attribute__((address_space(3))) void*)l, 16, 0, 0);
}
DEV float silu_f(float g) { return g / (1.f + __expf(-g)); }

// bijective XCD-chunk swizzle (m204)
DEV int xcd_swizzle(int orig, int nwg) {
  int q = nwg >> 3, r = nwg & 7;
  int xcd = orig & 7, pos = orig >> 3;
  return (xcd < r ? xcd * (q + 1) : r * (q + 1) + (xcd - r) * q) + pos;
}

DEV void sync_phase() {
  asm volatile("s_waitcnt vmcnt(0)" ::: "memory");
  __builtin_amdgcn_s_barrier();
  __builtin_amdgcn_sched_barrier(0);
}

enum { EPI_BF16 = 0, EPI_BIAS_BF16 = 1, EPI_GU = 6 };

// ================= 8-phase 256x256 bf16 GEMM (QKV) =========
template <int EPI>
__global__ __launch_bounds__(512, 2) void gemm8(
    const short* __restrict__ A, const short* __restrict__ W,
    const float* __restrict__ bias, void* __restrict__ outp,
    int M, int N, int K)
{
  __shared__ short lds[65536];  // 128 KiB
  const int tid = threadIdx.x;
  const int wid = tid >> 6, lane = tid & 63;
  const int wr = wid >> 2, wc = wid & 3;
  const int nwg = gridDim.x * gridDim.y;
  const int orig = blockIdx.y * gridDim.x + blockIdx.x;
  const int wg = xcd_swizzle(orig, nwg);
  const int bx = wg % gridDim.x, by = wg / gridDim.x;
  const int row0 = by * 256;
  const int c0 = bx * 256;

  f32x4 acc[8][4];
#pragma unroll
  for (int m = 0; m < 8; ++m)
#pragma unroll
    for (int n = 0; n < 4; ++n) acc[m][n] = f32x4{0.f, 0.f, 0.f, 0.f};

  const int srow = tid >> 3;
  const int k8s = (tid & 7) ^ (srow & 7);
  const short* aub[4];
  const short* bub[4];
#pragma unroll
  for (int u = 0; u < 4; ++u) {
    aub[u] = A + (size_t)(row0 + u * 64 + srow) * K + k8s * 8;
    bub[u] = W + (size_t)(c0 + u * 64 + srow) * K + k8s * 8;
  }
  const int ldw = wid * 512;

#define SA(d, u, kt) gload_lds16(aub[u] + (kt), &lds[(d)*16384 + (u)*4096 + ldw])
#define SB(d, u, kt) gload_lds16(bub[u] + (kt), &lds[32768 + (d)*16384 + (u)*4096 + ldw])
#define GATE(VN)                                              \
  asm volatile("s_waitcnt vmcnt(" #VN ")" ::: "memory");      \
  __builtin_amdgcn_s_barrier();                               \
  __builtin_amdgcn_sched_barrier(0);

  const int kg0 = (lane >> 4) ^ (lane & 7);
  const int kg1 = (4 + (lane >> 4)) ^ (lane & 7);
  const int aoff = (wr * 128 + (lane & 15)) * 64;
  const int boff = 32768 + (wc * 64 + (lane & 15)) * 64;

#define READ_B(d)                                                              \
  _Pragma("unroll") for (int n = 0; n < 4; ++n) {                              \
    bfr[0][n] = *(const s16x8*)&lds[(d)*16384 + boff + n * 1024 + kg0 * 8];    \
    bfr[1][n] = *(const s16x8*)&lds[(d)*16384 + boff + n * 1024 + kg1 * 8];    \
  }
#define DO_PHASE(d, p)                                                         \
  do {                                                                         \
    s16x8 a00 = *(const s16x8*)&lds[(d)*16384 + aoff + (2*(p))*1024 + kg0*8];  \
    s16x8 a01 = *(const s16x8*)&lds[(d)*16384 + aoff + (2*(p))*1024 + kg1*8];  \
    s16x8 a10 = *(const s16x8*)&lds[(d)*16384 + aoff + (2*(p)+1)*1024 + kg0*8];\
    s16x8 a11 = *(const s16x8*)&lds[(d)*16384 + aoff + (2*(p)+1)*1024 + kg1*8];\
    __builtin_amdgcn_s_setprio(1);                                             \
    _Pragma("unroll") for (int n = 0; n < 4; ++n)                              \
      acc[2*(p)][n] = __builtin_amdgcn_mfma_f32_16x16x32_bf16(a00, bfr[0][n], acc[2*(p)][n], 0, 0, 0); \
    _Pragma("unroll") for (int n = 0; n < 4; ++n)                              \
      acc[2*(p)+1][n] = __builtin_amdgcn_mfma_f32_16x16x32_bf16(a10, bfr[0][n], acc[2*(p)+1][n], 0, 0, 0); \
    _Pragma("unroll") for (int n = 0; n < 4; ++n)                              \
      acc[2*(p)][n] = __builtin_amdgcn_mfma_f32_16x16x32_bf16(a01, bfr[1][n], acc[2*(p)][n], 0, 0, 0); \
    _Pragma("unroll") for (int n = 0; n < 4; ++n)                              \
      acc[2*(p)+1][n] = __builtin_amdgcn_mfma_f32_16x16x32_bf16(a11, bfr[1][n], acc[2*(p)+1][n], 0, 0, 0); \
    __builtin_amdgcn_s_setprio(0);                                             \
  } while (0)

  SB(0, 0, 0); SB(0, 1, 0); SB(0, 2, 0); SB(0, 3, 0);
  SA(0, 0, 0); SA(0, 2, 0); SA(0, 1, 0); SA(0, 3, 0);

  const int NT = K >> 6;
  for (int t = 0; t < NT - 1; ++t) {
    const int d = t & 1, d1 = d ^ 1;
    const int kn = (t + 1) * 64;
    s16x8 bfr[2][4];
    SB(d1, 0, kn); SB(d1, 1, kn);
    GATE(4);
    READ_B(d);
    DO_PHASE(d, 0);
    SB(d1, 2, kn); SB(d1, 3, kn);
    DO_PHASE(d, 1);
    SA(d1, 0, kn); SA(d1, 2, kn);
    GATE(6);
    DO_PHASE(d, 2);
    SA(d1, 1, kn); SA(d1, 3, kn);
    DO_PHASE(d, 3);
  }
  {
    const int d = (NT - 1) & 1;
    s16x8 bfr[2][4];
    GATE(2);
    READ_B(d);
    DO_PHASE(d, 0);
    DO_PHASE(d, 1);
    GATE(0);
    DO_PHASE(d, 2);
    DO_PHASE(d, 3);
  }
#undef SA
#undef SB
#undef READ_B
#undef DO_PHASE
#undef GATE

  const int li = lane >> 4, lc = lane & 15;
#pragma unroll
  for (int m = 0; m < 8; ++m) {
#pragma unroll
    for (int i = 0; i < 4; ++i) {
      int gr = row0 + wr * 128 + m * 16 + li * 4 + i;
      if (gr >= M) continue;
#pragma unroll
      for (int n = 0; n < 4; ++n) {
        int gc = c0 + wc * 64 + n * 16 + lc;
        float v = acc[m][n][i];
        if (EPI == EPI_BIAS_BF16) v += bias[gc];
        ((short*)outp)[(size_t)gr * N + gc] = f2bf(v);
      }
    }
  }
}

// ====== GU GEMM v5: v4 structure + 32x32x16 MFMA (fewer reads/issues) ======
// 4 waves / 256 thr, 80 KiB LDS, 2 blocks/CU. Tile 64 rows x 128 gu-cols;
// wave (wr,wc): 32 rows x 64 cols as 2 n-blocks of 32x32, gate+up in regs.
// Per tile & wave: 4 A-reads + 8 B-reads (was 8+16), 16 MFMA of 32x32x16
// (was 32 of 16x16x32). Staging + gate algebra IDENTICAL to v4:
//   GATE(4) retires A+Bg of t -> gate MFMA (SAV/SBG of t+1 between halves)
//   -> GATE(6) retires Bu -> up MFMA (SBU of t+1). Peel: GATE(4)/GATE(0).
// A/B frag: lane l -> row (l&31), k-group (ks*2 + (l>>5)) ^ (row&7).
// C/D (m74/m101): col = lane&31, row = (reg&3) + 8*(reg>>2) + 4*(lane>>5).
__global__ __launch_bounds__(256, 2) void gemm8gu(
    const short* __restrict__ A, const short* __restrict__ Wg,
    const short* __restrict__ Wu, short* __restrict__ outp, int M, int K)
{
  __shared__ short lds[40960];  // 80 KiB
  const int tid = threadIdx.x;
  const int w = tid >> 6, lane = tid & 63;
  const int wr = w >> 1, wc = w & 1;
  const int l31 = lane & 31, lhi = lane >> 5;
  const int nwg = gridDim.x * gridDim.y;
  const int orig = blockIdx.y * gridDim.x + blockIdx.x;
  const int wg = xcd_swizzle(orig, nwg);
  const int bx = wg % gridDim.x, by = wg / gridDim.x;
  const int row0 = by * 64;
  const int colg = bx * 128;

  f32x16 accg[2], accu[2];
#pragma unroll
  for (int n = 0; n < 2; ++n)
#pragma unroll
    for (int r = 0; r < 16; ++r) { accg[n][r] = 0.f; accu[n][r] = 0.f; }

  // staging identical to v4
  const short* aptr[2];
#pragma unroll
  for (int i = 0; i < 2; ++i) {
    int r = (i * 4 + w) * 8 + (lane >> 3);
    int k8 = (lane & 7) ^ (r & 7);
    aptr[i] = A + (size_t)(row0 + r) * K + k8 * 8;
  }
  const short* bptr[8];
#pragma unroll
  for (int j = 0; j < 8; ++j) {
    int br = (j * 4 + w) * 8 + (lane >> 3);
    int k8 = (lane & 7) ^ (br & 7);
    bptr[j] = (br < 128 ? Wg + (size_t)(colg + br) * K
                        : Wu + (size_t)(colg + br - 128) * K) + k8 * 8;
  }

#define SAV(d, kt)                                                         \
  do {                                                                     \
    gload_lds16(aptr[0] + (kt), &lds[(d)*4096 + w * 512]);                 \
    gload_lds16(aptr[1] + (kt), &lds[(d)*4096 + 2048 + w * 512]);          \
  } while (0)
#define SBG(d, kt)                                                         \
  do {                                                                     \
    _Pragma("unroll") for (int j = 0; j < 4; ++j)                          \
        gload_lds16(bptr[j] + (kt), &lds[8192 + (d)*16384 + (j*4 + w)*512]);\
  } while (0)
#define SBU(d, kt)                                                         \
  do {                                                                     \
    _Pragma("unroll") for (int j = 4; j < 8; ++j)                          \
        gload_lds16(bptr[j] + (kt), &lds[8192 + (d)*16384 + (j*4 + w)*512]);\
  } while (0)
#define GATE(VN)                                              \
  asm volatile("s_waitcnt vmcnt(" #VN ")" ::: "memory");      \
  __builtin_amdgcn_s_barrier();                               \
  __builtin_amdgcn_sched_barrier(0);

  const int arow = wr * 32 + l31;              // A-region row
  const int kx = l31 & 7;                      // XOR key (row&7)
  const int browg = wc * 64 + l31;             // B gate base row (n adds 32)

  // frag reads: kg = (ks*2 + lhi) ^ kx  (row&7 == l31&7 for all bases)
#define READ_A32(d)                                                            \
  _Pragma("unroll") for (int ks = 0; ks < 4; ++ks)                             \
    af[ks] = *(const s16x8*)&lds[(d)*4096 + arow * 64 +                        \
                                 (((ks * 2 + lhi) ^ kx)) * 8];
#define READ_B32(d, ROWB, BF)                                                  \
  _Pragma("unroll") for (int n = 0; n < 2; ++n)                                \
    _Pragma("unroll") for (int ks = 0; ks < 4; ++ks)                           \
      BF[n][ks] = *(const s16x8*)&lds[8192 + (d)*16384 +                       \
                                      ((ROWB) + n * 32) * 64 +                 \
                                      (((ks * 2 + lhi) ^ kx)) * 8];
#define MM32(BF, ACC, KS0)                                                     \
  do {                                                                         \
    __builtin_amdgcn_s_setprio(1);                                             \
    _Pragma("unroll") for (int ks = KS0; ks < (KS0) + 2; ++ks)                 \
      _Pragma("unroll") for (int n = 0; n < 2; ++n)                            \
        ACC[n] = __builtin_amdgcn_mfma_f32_32x32x16_bf16(af[ks], BF[n][ks],    \
                                                         ACC[n], 0, 0, 0);     \
    __builtin_amdgcn_s_setprio(0);                                             \
  } while (0)

  // prologue: tile 0 -> buf 0 (A 2, Bg 4, Bu 4 = 10 loads/thread)
  SAV(0, 0); SBG(0, 0); SBU(0, 0);

  const int NT = K >> 6;
  for (int t = 0; t < NT - 1; ++t) {
    const int d = t & 1, d1 = d ^ 1;
    const int kn = (t + 1) * 64;
    s16x8 af[4], bg[2][4], bu[2][4];
    GATE(4);                    // A0-1, Bg0-3 of tile t complete
    READ_A32(d);
    READ_B32(d, browg, bg);
    MM32(bg, accg, 0);
    SAV(d1, kn);
    MM32(bg, accg, 2);
    SBG(d1, kn);
    GATE(6);                    // Bu0-3 of tile t complete
    READ_B32(d, browg + 128, bu);
    MM32(bu, accu, 0);
    SBU(d1, kn);
    MM32(bu, accu, 2);
  }
  {
    const int d = (NT - 1) & 1;
    s16x8 af[4], bg[2][4], bu[2][4];
    GATE(4);
    READ_A32(d);
    READ_B32(d, browg, bg);
    MM32(bg, accg, 0);
    MM32(bg, accg, 2);
    GATE(0);
    READ_B32(d, browg + 128, bu);
    MM32(bu, accu, 0);
    MM32(bu, accu, 2);
  }
#undef SAV
#undef SBG
#undef SBU
#undef READ_A32
#undef READ_B32
#undef MM32
#undef GATE

  // epilogue: C/D 32x32 layout -> silu(gate)*up, bf16 store
#pragma unroll
  for (int n = 0; n < 2; ++n) {
    int gc = colg + wc * 64 + n * 32 + l31;
#pragma unroll
    for (int r = 0; r < 16; ++r) {
      int gr = row0 + wr * 32 + (r & 3) + 8 * (r >> 2) + 4 * lhi;
      if (gr < M)
        outp[(size_t)gr * 1536 + gc] = f2bf(silu_f(accg[n][r]) * accu[n][r]);
    }
  }
}

// ====== fused GEMM + residual + RMS (BM=128, BN=512, single round) =========
template <int PROJ>
__global__ __launch_bounds__(512, 1) void gemm_norm(
    const short* __restrict__ A, const short* __restrict__ W,
    const float* __restrict__ bias, const short* __restrict__ residb,
    float* __restrict__ outf, short* __restrict__ hsb, int K)
{
  __shared__ short lds[81920];  // 160 KiB
  const int tid = threadIdx.x;
  const int wid = tid >> 6, lane = tid & 63;
  const int wr = wid >> 2, wc = wid & 3;
  const int row0 = blockIdx.x * 128;
  const int tid8 = tid * 8;

  f32x4 acc[4][8];
#pragma unroll
  for (int m = 0; m < 4; ++m)
#pragma unroll
    for (int n = 0; n < 8; ++n) acc[m][n] = f32x4{0.f, 0.f, 0.f, 0.f};

  const int srow = tid >> 3;
  const int k8s = (tid & 7) ^ (srow & 7);
  const short* aptr[2];
#pragma unroll
  for (int i = 0; i < 2; ++i)
    aptr[i] = A + (size_t)(row0 + i * 64 + srow) * K + k8s * 8;
  const short* bptr[8];
#pragma unroll
  for (int u = 0; u < 8; ++u)
    bptr[u] = W + (size_t)(u * 64 + srow) * K + k8s * 8;

#define STG(d, kt)                                                            \
  do {                                                                        \
    _Pragma("unroll") for (int i = 0; i < 2; ++i)                             \
        gload_lds16(aptr[i] + (kt), &lds[(d)*8192 + i*4096 + tid8]);          \
    _Pragma("unroll") for (int u = 0; u < 8; ++u)                             \
        gload_lds16(bptr[u] + (kt), &lds[16384 + (d)*32768 + u*4096 + tid8]); \
  } while (0)
#define GATEN(VN)                                             \
  asm volatile("s_waitcnt vmcnt(" #VN ")" ::: "memory");      \
  __builtin_amdgcn_s_barrier();                               \
  __builtin_amdgcn_sched_barrier(0);

  const int kg0 = (lane >> 4) ^ (lane & 7);
  const int kg1 = (4 + (lane >> 4)) ^ (lane & 7);
  const int arow = (wr * 64 + (lane & 15)) * 64;
  const int brow0 = (wc * 128 + (lane & 15)) * 64;

  STG(0, 0);
  const int NT = K >> 6;
  for (int t = 0; t < NT; ++t) {
    const int d = t & 1;
    if (t + 1 < NT) {
      STG(d ^ 1, (t + 1) * 64);
      GATEN(10);
    } else {
      GATEN(0);
    }
    s16x8 af0[4], af1[4];
#pragma unroll
    for (int m = 0; m < 4; ++m) {
      af0[m] = *(const s16x8*)&lds[d * 8192 + arow + m * 1024 + kg0 * 8];
      af1[m] = *(const s16x8*)&lds[d * 8192 + arow + m * 1024 + kg1 * 8];
    }
    __builtin_amdgcn_s_setprio(1);
#pragma unroll
    for (int n = 0; n < 8; ++n) {
      int bo = 16384 + d * 32768 + brow0 + n * 1024;
      s16x8 b0 = *(const s16x8*)&lds[bo + kg0 * 8];
      s16x8 b1 = *(const s16x8*)&lds[bo + kg1 * 8];
#pragma unroll
      for (int m = 0; m < 4; ++m)
        acc[m][n] = __builtin_amdgcn_mfma_f32_16x16x32_bf16(af0[m], b0, acc[m][n], 0, 0, 0);
#pragma unroll
      for (int m = 0; m < 4; ++m)
        acc[m][n] = __builtin_amdgcn_mfma_f32_16x16x32_bf16(af1[m], b1, acc[m][n], 0, 0, 0);
    }
    __builtin_amdgcn_s_setprio(0);
    __builtin_amdgcn_s_barrier();
  }
#undef STG
#undef GATEN

  const int li = lane >> 4, lc = lane & 15;
  float* fbuf = (float*)lds;
#pragma unroll
  for (int m = 0; m < 4; ++m) {
#pragma unroll
    for (int i = 0; i < 4; ++i) {
      int rowl = wr * 64 + m * 16 + li * 4 + i;
      int gr = row0 + rowl;
      float s = 0.f;
#pragma unroll
      for (int n = 0; n < 8; ++n) {
        int gc = wc * 128 + n * 16 + lc;
        float v = acc[m][n][i];
        if (PROJ) v += bias[gc] + bf2f(residb[(size_t)gr * 512 + gc]);
        else      v += outf[(size_t)gr * 512 + gc];
        acc[m][n][i] = v;
        s += v * v;
      }
      s += __shfl_xor(s, 1, 64);
      s += __shfl_xor(s, 2, 64);
      s += __shfl_xor(s, 4, 64);
      s += __shfl_xor(s, 8, 64);
      if (lc == 0) fbuf[rowl * 4 + wc] = s;
    }
  }
  __builtin_amdgcn_s_barrier();
#pragma unroll
  for (int m = 0; m < 4; ++m) {
#pragma unroll
    for (int i = 0; i < 4; ++i) {
      int rowl = wr * 64 + m * 16 + li * 4 + i;
      int gr = row0 + rowl;
      float tot = fbuf[rowl * 4] + fbuf[rowl * 4 + 1] + fbuf[rowl * 4 + 2] + fbuf[rowl * 4 + 3];
      float sc = rsqrtf(tot * (1.f / 512.f) + 1e-5f);
      size_t orow;
      if (PROJ) {
        int b = gr / 900, rem = gr % 900;
        int w = rem / 9, n_ = rem % 9;
        int wi = w / 10, wj = w % 10;
        int ii = n_ / 3, jj = n_ % 3;
        int gy = wi * 3 + ii + 1; if (gy >= 30) gy -= 30;
        int gx = wj * 3 + jj + 1; if (gx >= 30) gx -= 30;
        orow = ((size_t)b * 916 + 16 + gy * 30 + gx);
      } else {
        orow = (size_t)gr;
      }
#pragma unroll
      for (int n = 0; n < 8; ++n) {
        int gc = wc * 128 + n * 16 + lc;
        float v = acc[m][n][i] * sc;
        outf[orow * 512 + gc] = v;
        if (PROJ) hsb[orow * 512 + gc] = f2bf(v);
      }
    }
  }
}

// ================= 2-phase 128x128 GEMM (small prefix GEMMs) =====
template <int EPI>
__global__ __launch_bounds__(256) void gemm2(
    const short* __restrict__ A, const short* __restrict__ W,
    const short* __restrict__ Wu, const float* __restrict__ bias,
    void* __restrict__ outp, int M, int N, int K)
{
  __shared__ short As0[8192], Bs0[8192];
  __shared__ short As1[8192], Bs1[8192];
  const int tid = threadIdx.x;
  const int wave = tid >> 6, lane = tid & 63;
  const int nwg = gridDim.x * gridDim.y;
  const int orig = blockIdx.y * gridDim.x + blockIdx.x;
  const int wg = xcd_swizzle(orig, nwg);
  const int bx = wg % gridDim.x, by = wg / gridDim.x;
  const int row0 = by * 128;
  const int col0 = (EPI == EPI_GU) ? bx * 64 : bx * 128;
  const int wr = wave >> 1, wc = wave & 1;

  f32x4 acc[4][4];
#pragma unroll
  for (int m = 0; m < 4; ++m)
#pragma unroll
    for (int n = 0; n < 4; ++n) acc[m][n] = f32x4{0.f, 0.f, 0.f, 0.f};

  const short* aptr[4];
  const short* bptr[4];
  int ldst[4];
#pragma unroll
  for (int i = 0; i < 4; ++i) {
    int e = i * 2048 + tid * 8;
    int srow = e >> 6;
    int skg = ((e >> 3) & 7) ^ (srow & 7);
    aptr[i] = A + (size_t)(row0 + srow) * K + skg * 8;
    if (EPI == EPI_GU)
      bptr[i] = (srow < 64 ? W + (size_t)(col0 + srow) * K
                           : Wu + (size_t)(col0 + srow - 64) * K) + skg * 8;
    else
      bptr[i] = W + (size_t)(col0 + srow) * K + skg * 8;
    ldst[i] = i * 2048 + wave * 512;
  }

#define STAGE(AS, BS, KT)                                   \
  do {                                                      \
    _Pragma("unroll") for (int i = 0; i < 4; ++i)           \
        gload_lds16(aptr[i] + (KT), &AS[ldst[i]]);          \
    _Pragma("unroll") for (int i = 0; i < 4; ++i)           \
        gload_lds16(bptr[i] + (KT), &BS[ldst[i]]);          \
  } while (0)

#define COMPUTE(AS, BS)                                                        \
  do {                                                                         \
    _Pragma("unroll") for (int ks = 0; ks < 2; ++ks) {                         \
      s16x8 af[4], bfr[4];                                                     \
      _Pragma("unroll") for (int m = 0; m < 4; ++m) {                          \
        int row = wr * 64 + m * 16 + (lane & 15);                              \
        int kg = (ks * 4 + (lane >> 4)) ^ (row & 7);                           \
        af[m] = *(const s16x8*)&AS[row * 64 + kg * 8];                         \
      }                                                                        \
      _Pragma("unroll") for (int n = 0; n < 4; ++n) {                          \
        int brow = (EPI == EPI_GU)                                             \
                       ? ((n < 2 ? wc * 32 + n * 16                            \
                                 : 64 + wc * 32 + (n - 2) * 16) + (lane & 15)) \
                       : (wc * 64 + n * 16 + (lane & 15));                     \
        int kg = (ks * 4 + (lane >> 4)) ^ (brow & 7);                          \
        bfr[n] = *(const s16x8*)&BS[brow * 64 + kg * 8];                       \
      }                                                                        \
      _Pragma("unroll") for (int m = 0; m < 4; ++m)                            \
          _Pragma("unroll") for (int n = 0; n < 4; ++n)                        \
              acc[m][n] = __builtin_amdgcn_mfma_f32_16x16x32_bf16(             \
                  af[m], bfr[n], acc[m][n], 0, 0, 0);                          \
    }                                                                          \
  } while (0)

  STAGE(As0, Bs0, 0);
  sync_phase();
  for (int kt = 0; kt < K; kt += 128) {
    STAGE(As1, Bs1, kt + 64);
    COMPUTE(As0, Bs0);
    sync_phase();
    if (kt + 128 < K) STAGE(As0, Bs0, kt + 128);
    COMPUTE(As1, Bs1);
    if (kt + 128 < K) sync_phase();
  }
#undef STAGE
#undef COMPUTE

  const int lr = (lane >> 4) * 4, lc = lane & 15;
#pragma unroll
  for (int m = 0; m < 4; ++m) {
#pragma unroll
    for (int i = 0; i < 4; ++i) {
      int gr = row0 + wr * 64 + m * 16 + lr + i;
      if (EPI == EPI_GU) {
#pragma unroll
        for (int n = 0; n < 2; ++n) {
          int gc = col0 + wc * 32 + n * 16 + lc;
          float v = silu_f(acc[m][n][i]) * acc[m][n + 2][i];
          ((short*)outp)[(size_t)gr * N + gc] = f2bf(v);
        }
      } else {
#pragma unroll
        for (int n = 0; n < 4; ++n) {
          int gc = col0 + wc * 64 + n * 16 + lc;
          ((short*)outp)[(size_t)gr * N + gc] = f2bf(acc[m][n][i]);
        }
      }
    }
  }
}

// -------- fused weight conversion + prefix rows (one kernel) ---------------
// segments (float4 units): weights 1441792 (contiguous dst) | prefix 65536
__global__ __launch_bounds__(256) void cvt_all_kernel(
    const float* __restrict__ s_qkv, const float* __restrict__ s_proj,
    const float* __restrict__ s_gu, const float* __restrict__ s_down,
    const float* __restrict__ s_pgu, const float* __restrict__ s_pdown,
    const float* __restrict__ hs, short* __restrict__ dst,
    short* __restrict__ prefb) {
  int i = blockIdx.x * 256 + threadIdx.x;
  if (i >= 1507328) return;
  if (i >= 1441792) {
    int p = i - 1441792;             // 512 rows x 128 float4
    int r = p >> 7, c4 = p & 127;
    int b = r >> 4, t = r & 15;
    f32x4 v = *(const f32x4*)(hs + ((size_t)b * 916 + t) * 512 + c4 * 4);
    s16x4 o;
#pragma unroll
    for (int e = 0; e < 4; ++e) o[e] = f2bf(v[e]);
    *(s16x4*)(prefb + (size_t)r * 512 + c4 * 4) = o;
    return;
  }
  const float* src;
  int base;
  if (i < 262144) {
    if (i < 196608) { src = s_qkv; base = 0; }
    else            { src = s_proj; base = 196608; }
  } else if (i < 851968) {
    if (i < 655360) { src = s_gu; base = 262144; }
    else            { src = s_down; base = 655360; }
  } else {
    if (i < 1245184) { src = s_pgu; base = 851968; }
    else             { src = s_pdown; base = 1245184; }
  }
  f32x4 v = *(const f32x4*)(src + (size_t)(i - base) * 4);
  s16x4 o;
#pragma unroll
  for (int e = 0; e < 4; ++e) o[e] = f2bf(v[e]);
  *(s16x4*)(dst + (size_t)i * 4) = o;
}

__global__ __launch_bounds__(512) void mean_kernel(const float* __restrict__ hs,
                                                   float* __restrict__ m) {
  int b = blockIdx.x, d = threadIdx.x;
  float s = 0.f;
#pragma unroll
  for (int t = 0; t < 16; ++t) s += hs[((size_t)b * 916 + t) * 512 + d];
  m[b * 512 + d] = s * (1.f / 16.f);
}

// grid = hs[:,16:] + mean -> bf16 window-partitioned xw
__global__ __launch_bounds__(256) void prep_kernel(const float* __restrict__ hs,
                                                   const float* __restrict__ m,
                                                   short* __restrict__ xw) {
  int idx = blockIdx.x * 256 + threadIdx.x;
  if (idx >= 32 * 900 * 128) return;
  int c4 = idx & 127;
  int row = idx >> 7;
  int b = row / 900, rem = row % 900;
  int gy = rem / 30, gx = rem % 30;
  f32x4 v = *(const f32x4*)(hs + ((size_t)b * 916 + 16 + rem) * 512 + c4 * 4);
  f32x4 mm = *(const f32x4*)(m + b * 512 + c4 * 4);
  v += mm;
  int ry = gy + 29; if (ry >= 30) ry -= 30;
  int rx = gx + 29; if (rx >= 30) rx -= 30;
  int wi = ry / 3, ii = ry % 3, wj = rx / 3, jj = rx % 3;
  size_t xrow = (size_t)((b * 100 + wi * 10 + wj) * 9 + ii * 3 + jj);
  s16x4 o;
#pragma unroll
  for (int e = 0; e < 4; ++e) o[e] = f2bf(v[e]);
  *(s16x4*)(xw + xrow * 512 + c4 * 4) = o;
}

// ---------------- windowed attention (9 tokens, 8 heads per window) ----------
__global__ __launch_bounds__(256) void attn_kernel(const short* __restrict__ qkv,
                                                   const float* __restrict__ rel_bias,
                                                   short* __restrict__ outp) {
  __shared__ short sq[9 * 512];
  __shared__ short sk[9 * 512];
  __shared__ short sv[9 * 512];
  __shared__ float sS[648];
  const int wlin = blockIdx.x;
  const int w = wlin % 100;
  const int wi = w / 10, wj = w % 10;
  const int tid = threadIdx.x;
  const short* base = qkv + (size_t)wlin * 9 * 1536;
  for (int idx = tid; idx < 1728; idx += 256) {
    int n = idx / 192, c8 = idx % 192;
    s16x8 v = *(const s16x8*)(base + (size_t)n * 1536 + c8 * 8);
    int which = c8 >> 6;
    short* dst = (which == 0) ? sq : (which == 1) ? sk : sv;
    *(s16x8*)(dst + n * 512 + (c8 & 63) * 8) = v;
  }
  __syncthreads();
  for (int idx = tid; idx < 648; idx += 256) {
    int h = idx / 81, r = idx % 81, i = r / 9, j = r % 9;
    const short* qp = sq + i * 512 + h * 64;
    const short* kp = sk + j * 512 + h * 64;
    float dot = 0.f;
#pragma unroll
    for (int c = 0; c < 8; ++c) {
      s16x8 qv = *(const s16x8*)(qp + c * 8);
      s16x8 kv = *(const s16x8*)(kp + c * 8);
#pragma unroll
      for (int e = 0; e < 8; ++e) dot += bf2f(qv[e]) * bf2f(kv[e]);
    }
    float s = dot * 0.125f;
    int ia = i / 3, ja = i % 3, ib = j / 3, jb = j % 3;
    s += rel_bias[(5 * (ia - ib + 2) + (ja - jb + 2)) * 8 + h];
    int ra = wi * 3 + ia, ca = wj * 3 + ja, rb = wi * 3 + ib, cb = wj * 3 + jb;
    int rga = (ra < 27) ? 0 : (ra < 29) ? 1 : 2;
    int cga = (ca < 27) ? 0 : (ca < 29) ? 1 : 2;
    int rgb = (rb < 27) ? 0 : (rb < 29) ? 1 : 2;
    int cgb = (cb < 27) ? 0 : (cb < 29) ? 1 : 2;
    if (rga * 3 + cga != rgb * 3 + cgb) s -= 100.f;
    sS[idx] = s;
  }
  __syncthreads();
  if (tid < 72) {
    float* row = sS + tid * 9;
    float mx = row[0];
#pragma unroll
    for (int j = 1; j < 9; ++j) mx = fmaxf(mx, row[j]);
    float e[9], sum = 0.f;
#pragma unroll
    for (int j = 0; j < 9; ++j) { e[j] = __expf(row[j] - mx); sum += e[j]; }
    float inv = 1.f / sum;
#pragma unroll
    for (int j = 0; j < 9; ++j) row[j] = e[j] * inv;
  }
  __syncthreads();
  for (int idx = tid; idx < 576; idx += 256) {
    int h = idx / 72, r = idx % 72, i = r / 8, d8 = r % 8;
    const float* p = sS + (h * 9 + i) * 9;
    float a[8] = {0, 0, 0, 0, 0, 0, 0, 0};
#pragma unroll
    for (int j = 0; j < 9; ++j) {
      float pj = p[j];
      s16x8 vv = *(const s16x8*)(sv + j * 512 + h * 64 + d8 * 8);
#pragma unroll
      for (int e = 0; e < 8; ++e) a[e] += pj * bf2f(vv[e]);
    }
    s16x8 o;
#pragma unroll
    for (int e = 0; e < 8; ++e) o[e] = f2bf(a[e]);
    *(s16x8*)(outp + ((size_t)wlin * 9 + i) * 512 + h * 64 + d8 * 8) = o;
  }
}

// ---------------- prefix add + RMS norm (4 rows per block) -----------------
__global__ __launch_bounds__(256) void prefix_addnorm_kernel(const float* __restrict__ hs,
                                                             const short* __restrict__ pd,
                                                             float* __restrict__ out,
                                                             short* __restrict__ hsb) {
  int r = blockIdx.x * 4 + (threadIdx.x >> 6);
  int lane = threadIdx.x & 63;
  int b = r >> 4, t = r & 15;
  size_t orow = ((size_t)b * 916 + t) * 512 + lane * 8;
  f32x4 a0 = *(const f32x4*)(hs + orow);
  f32x4 a1 = *(const f32x4*)(hs + orow + 4);
  s16x8 d8 = *(const s16x8*)(pd + (size_t)r * 512 + lane * 8);
  float x[8];
  float ss = 0.f;
#pragma unroll
  for (int e = 0; e < 8; ++e) {
    x[e] = (e < 4 ? a0[e] : a1[e - 4]) + bf2f(d8[e]);
    ss += x[e] * x[e];
  }
  ss = wave_allsum(ss);
  float sc = rsqrtf(ss * (1.f / 512.f) + 1e-5f);
  s16x8 o;
#pragma unroll
  for (int e = 0; e < 8; ++e) {
    x[e] *= sc;
    o[e] = f2bf(x[e]);
  }
  *(f32x4*)(out + orow) = f32x4{x[0], x[1], x[2], x[3]};
  *(f32x4*)(out + orow + 4) = f32x4{x[4], x[5], x[6], x[7]};
  *(s16x8*)(hsb + orow) = o;
}

// ---------------- workspace layout (bytes; liveness-overlaid) ----------------
static constexpr size_t OFF_WQKV   = 0;
static constexpr size_t OFF_WPROJ  = 1572864;
static constexpr size_t OFF_WGU    = 2097152;
static constexpr size_t OFF_WDOWN  = 5242880;
static constexpr size_t OFF_WPGU   = 6815744;
static constexpr size_t OFF_WPDOWN = 9961472;   // weights end 11534336
static constexpr size_t OFF_MEAN   = 11534336;
static constexpr size_t OFF_PREFB  = 11599872;
static constexpr size_t OFF_PINTER = 13697024;
static constexpr size_t OFF_PDOUT  = 15269888;  // end 15794176
static constexpr size_t OFF_XW     = 16777216;  // 28800*512*2 -> 46268416 (live 2..5)
static constexpr size_t OFF_QKV    = 46399488;  // 28800*1536*2 -> 134873088 (live 3..4)
static constexpr size_t OFF_ATTNO  = 134873088; // 28800*512*2 -> 164364288 (live 4..5)
static constexpr size_t OFF_INTER  = OFF_XW;    // 29312*1536*2 -> 106823680 (live 7..8)
static constexpr size_t OFF_HSB    = 164364288; // 29312*512*2 -> 194379776 (live 5..7)

extern "C" void kernel_launch(void* const* d_in, const int* in_sizes, int n_in,
                              void* d_out, int out_size, void* d_ws, size_t ws_size,
                              hipStream_t stream) {
  const float* hs      = (const float*)d_in[0];
  const float* qkv_w   = (const float*)d_in[1];
  const float* qkv_b   = (const float*)d_in[2];
  const float* proj_w  = (const float*)d_in[3];
  const float* proj_b  = (const float*)d_in[4];
  const float* rel_b   = (const float*)d_in[5];
  const float* gu_w    = (const float*)d_in[6];
  const float* down_w  = (const float*)d_in[7];
  const float* pgu_w   = (const float*)d_in[8];
  const float* pdown_w = (const float*)d_in[9];

  char* ws = (char*)d_ws;
  short* Wqkv   = (short*)(ws + OFF_WQKV);
  short* Wproj  = (short*)(ws + OFF_WPROJ);
  short* Wgu    = (short*)(ws + OFF_WGU);
  short* Wdown  = (short*)(ws + OFF_WDOWN);
  short* Wpgu   = (short*)(ws + OFF_WPGU);
  short* Wpdown = (short*)(ws + OFF_WPDOWN);
  float* meanb  = (float*)(ws + OFF_MEAN);
  short* prefb  = (short*)(ws + OFF_PREFB);
  short* pinter = (short*)(ws + OFF_PINTER);
  short* pdout  = (short*)(ws + OFF_PDOUT);
  short* xw     = (short*)(ws + OFF_XW);
  short* qkvb   = (short*)(ws + OFF_QKV);
  short* attno  = (short*)(ws + OFF_ATTNO);
  short* interb = (short*)(ws + OFF_INTER);
  short* hsb    = (short*)(ws + OFF_HSB);
  float* outf   = (float*)d_out;

  // 1. all weights fp32 -> bf16 + prefix rows (one kernel)
  cvt_all_kernel<<<5888, 256, 0, stream>>>(qkv_w, proj_w, gu_w, down_w,
                                           pgu_w, pdown_w, hs, (short*)ws, prefb);

  // 2. prefix mean -> windowed bf16 input
  mean_kernel<<<32, 512, 0, stream>>>(hs, meanb);
  prep_kernel<<<14400, 256, 0, stream>>>(hs, meanb, xw);

  // 3. QKV projection (M=28800, N=1536, K=512)
  gemm8<EPI_BIAS_BF16><<<dim3(6, 113), 512, 0, stream>>>(
      xw, Wqkv, qkv_b, qkvb, 28800, 1536, 512);
  // 4. windowed attention
  attn_kernel<<<3200, 256, 0, stream>>>(qkvb, rel_b, attno);

  // 5. fused proj + bias + residual(xw) + RMS + roll-scatter
  gemm_norm<1><<<225, 512, 0, stream>>>(attno, Wproj, proj_b, xw, outf, hsb, 512);

  // 6. prefix branch: swiglu + down + rms (fills prefix rows of outf/hsb)
  gemm2<EPI_GU><<<dim3(24, 4), 256, 0, stream>>>(
      prefb, Wpgu, Wpgu + 1536 * 512, nullptr, pinter, 512, 1536, 512);
  gemm2<EPI_BF16><<<dim3(4, 4), 256, 0, stream>>>(
      pinter, Wpdown, nullptr, nullptr, pdout, 512, 512, 1536);
  prefix_addnorm_kernel<<<128, 256, 0, stream>>>(hs, pdout, outf, hsb);

  // 7. full-sequence fused swiglu (M=29312, v5 32x32 MFMA, 2 blocks/CU)
  gemm8gu<<<dim3(12, 458), 256, 0, stream>>>(
      hsb, Wgu, Wgu + 1536 * 512, interb, 29312, 512);
  // 8. fused down + residual(outf) + RMS in place (final output)
  gemm_norm<0><<<229, 512, 0, stream>>>(interb, Wdown, nullptr, nullptr, outf,
                                        nullptr, 1536);

  (void)in_sizes; (void)n_in; (void)out_size; (void)ws_size;
}

// Round 12
// 425.569 us; speedup vs baseline: 1.0667x; 1.0667x over previous
//
#include <hip/hip_runtime.h>
#include <cstdint>
#include <cstddef>

typedef float f32x4 __attribute__((ext_vector_type(4)));
typedef short s16x8 __attribute__((ext_vector_type(8)));
typedef short s16x4 __attribute__((ext_vector_type(4)));

#define DEV static __device__ __forceinline__

DEV float bf2f(short s) {
  union { unsigned u; float f; } c;
  c.u = ((unsigned)(unsigned short)s) << 16;
  return c.f;
}
DEV short f2bf(float f) {
  union { float f; unsigned u; } c;
  c.f = f;
  unsigned r = c.u + 0x7fffu + ((c.u >> 16) & 1u);
  return (short)(r >> 16);
}
DEV float wave_allsum(float v) {
#pragma unroll
  for (int off = 32; off > 0; off >>= 1) v += __shfl_xor(v, off, 64);
  return v;
}
DEV void gload_lds16(const void* g, void* l) {
  __builtin_amdgcn_global_load_lds(
      (const __attribute__((address_space(1))) void*)g,
      (__attribute__((address_space(3))) void*)l, 16, 0, 0);
}
DEV float silu_f(float g) { return g / (1.f + __expf(-g)); }

// bijective XCD-chunk swizzle (m204)
DEV int xcd_swizzle(int orig, int nwg) {
  int q = nwg >> 3, r = nwg & 7;
  int xcd = orig & 7, pos = orig >> 3;
  return (xcd < r ? xcd * (q + 1) : r * (q + 1) + (xcd - r) * q) + pos;
}

DEV void sync_phase() {
  asm volatile("s_waitcnt vmcnt(0)" ::: "memory");
  __builtin_amdgcn_s_barrier();
  __builtin_amdgcn_sched_barrier(0);
}

enum { EPI_BF16 = 0, EPI_BIAS_BF16 = 1, EPI_GU = 6 };

// ================= 8-phase 256x256 bf16 GEMM (QKV) =========
template <int EPI>
__global__ __launch_bounds__(512, 2) void gemm8(
    const short* __restrict__ A, const short* __restrict__ W,
    const float* __restrict__ bias, void* __restrict__ outp,
    int M, int N, int K)
{
  __shared__ short lds[65536];  // 128 KiB
  const int tid = threadIdx.x;
  const int wid = tid >> 6, lane = tid & 63;
  const int wr = wid >> 2, wc = wid & 3;
  const int nwg = gridDim.x * gridDim.y;
  const int orig = blockIdx.y * gridDim.x + blockIdx.x;
  const int wg = xcd_swizzle(orig, nwg);
  const int bx = wg % gridDim.x, by = wg / gridDim.x;
  const int row0 = by * 256;
  const int c0 = bx * 256;

  f32x4 acc[8][4];
#pragma unroll
  for (int m = 0; m < 8; ++m)
#pragma unroll
    for (int n = 0; n < 4; ++n) acc[m][n] = f32x4{0.f, 0.f, 0.f, 0.f};

  const int srow = tid >> 3;
  const int k8s = (tid & 7) ^ (srow & 7);
  const short* aub[4];
  const short* bub[4];
#pragma unroll
  for (int u = 0; u < 4; ++u) {
    aub[u] = A + (size_t)(row0 + u * 64 + srow) * K + k8s * 8;
    bub[u] = W + (size_t)(c0 + u * 64 + srow) * K + k8s * 8;
  }
  const int ldw = wid * 512;

#define SA(d, u, kt) gload_lds16(aub[u] + (kt), &lds[(d)*16384 + (u)*4096 + ldw])
#define SB(d, u, kt) gload_lds16(bub[u] + (kt), &lds[32768 + (d)*16384 + (u)*4096 + ldw])
#define GATE(VN)                                              \
  asm volatile("s_waitcnt vmcnt(" #VN ")" ::: "memory");      \
  __builtin_amdgcn_s_barrier();                               \
  __builtin_amdgcn_sched_barrier(0);

  const int kg0 = (lane >> 4) ^ (lane & 7);
  const int kg1 = (4 + (lane >> 4)) ^ (lane & 7);
  const int aoff = (wr * 128 + (lane & 15)) * 64;
  const int boff = 32768 + (wc * 64 + (lane & 15)) * 64;

#define READ_B(d)                                                              \
  _Pragma("unroll") for (int n = 0; n < 4; ++n) {                              \
    bfr[0][n] = *(const s16x8*)&lds[(d)*16384 + boff + n * 1024 + kg0 * 8];    \
    bfr[1][n] = *(const s16x8*)&lds[(d)*16384 + boff + n * 1024 + kg1 * 8];    \
  }
#define DO_PHASE(d, p)                                                         \
  do {                                                                         \
    s16x8 a00 = *(const s16x8*)&lds[(d)*16384 + aoff + (2*(p))*1024 + kg0*8];  \
    s16x8 a01 = *(const s16x8*)&lds[(d)*16384 + aoff + (2*(p))*1024 + kg1*8];  \
    s16x8 a10 = *(const s16x8*)&lds[(d)*16384 + aoff + (2*(p)+1)*1024 + kg0*8];\
    s16x8 a11 = *(const s16x8*)&lds[(d)*16384 + aoff + (2*(p)+1)*1024 + kg1*8];\
    __builtin_amdgcn_s_setprio(1);                                             \
    _Pragma("unroll") for (int n = 0; n < 4; ++n)                              \
      acc[2*(p)][n] = __builtin_amdgcn_mfma_f32_16x16x32_bf16(a00, bfr[0][n], acc[2*(p)][n], 0, 0, 0); \
    _Pragma("unroll") for (int n = 0; n < 4; ++n)                              \
      acc[2*(p)+1][n] = __builtin_amdgcn_mfma_f32_16x16x32_bf16(a10, bfr[0][n], acc[2*(p)+1][n], 0, 0, 0); \
    _Pragma("unroll") for (int n = 0; n < 4; ++n)                              \
      acc[2*(p)][n] = __builtin_amdgcn_mfma_f32_16x16x32_bf16(a01, bfr[1][n], acc[2*(p)][n], 0, 0, 0); \
    _Pragma("unroll") for (int n = 0; n < 4; ++n)                              \
      acc[2*(p)+1][n] = __builtin_amdgcn_mfma_f32_16x16x32_bf16(a11, bfr[1][n], acc[2*(p)+1][n], 0, 0, 0); \
    __builtin_amdgcn_s_setprio(0);                                             \
  } while (0)

  SB(0, 0, 0); SB(0, 1, 0); SB(0, 2, 0); SB(0, 3, 0);
  SA(0, 0, 0); SA(0, 2, 0); SA(0, 1, 0); SA(0, 3, 0);

  const int NT = K >> 6;
  for (int t = 0; t < NT - 1; ++t) {
    const int d = t & 1, d1 = d ^ 1;
    const int kn = (t + 1) * 64;
    s16x8 bfr[2][4];
    SB(d1, 0, kn); SB(d1, 1, kn);
    GATE(4);
    READ_B(d);
    DO_PHASE(d, 0);
    SB(d1, 2, kn); SB(d1, 3, kn);
    DO_PHASE(d, 1);
    SA(d1, 0, kn); SA(d1, 2, kn);
    GATE(6);
    DO_PHASE(d, 2);
    SA(d1, 1, kn); SA(d1, 3, kn);
    DO_PHASE(d, 3);
  }
  {
    const int d = (NT - 1) & 1;
    s16x8 bfr[2][4];
    GATE(2);
    READ_B(d);
    DO_PHASE(d, 0);
    DO_PHASE(d, 1);
    GATE(0);
    DO_PHASE(d, 2);
    DO_PHASE(d, 3);
  }
#undef SA
#undef SB
#undef READ_B
#undef DO_PHASE
#undef GATE

  const int li = lane >> 4, lc = lane & 15;
#pragma unroll
  for (int m = 0; m < 8; ++m) {
#pragma unroll
    for (int i = 0; i < 4; ++i) {
      int gr = row0 + wr * 128 + m * 16 + li * 4 + i;
      if (gr >= M) continue;
#pragma unroll
      for (int n = 0; n < 4; ++n) {
        int gc = c0 + wc * 64 + n * 16 + lc;
        float v = acc[m][n][i];
        if (EPI == EPI_BIAS_BF16) v += bias[gc];
        ((short*)outp)[(size_t)gr * N + gc] = f2bf(v);
      }
    }
  }
}

// ============ GU GEMM v4 (PROVEN BEST): 4-wave/256-thr, 80 KiB, 2 blk/CU ====
// Tile 64 rows x 128 gu-cols; wave (wr,wc): 32 rows x 64 cols, gate+up in
// registers, A-frags read once & reused. 16x16x32 MFMA (32x32 regressed:
// 32-lane row-groups over 64-wide K-rows give unavoidable 4-way LDS bank
// conflicts — only 8 16B column slots per row; measured 1.4e7 conflicts).
// Gates: GATE(4) retires A+Bg of t -> gate MFMA (stage A,Bg of t+1) ->
// GATE(6) retires Bu -> up MFMA (stage Bu). Peel: GATE(4)/GATE(0).
__global__ __launch_bounds__(256, 2) void gemm8gu(
    const short* __restrict__ A, const short* __restrict__ Wg,
    const short* __restrict__ Wu, short* __restrict__ outp, int M, int K)
{
  __shared__ short lds[40960];  // 80 KiB
  const int tid = threadIdx.x;
  const int w = tid >> 6, lane = tid & 63;
  const int wr = w >> 1, wc = w & 1;
  const int nwg = gridDim.x * gridDim.y;
  const int orig = blockIdx.y * gridDim.x + blockIdx.x;
  const int wg = xcd_swizzle(orig, nwg);
  const int bx = wg % gridDim.x, by = wg / gridDim.x;
  const int row0 = by * 64;
  const int colg = bx * 128;

  f32x4 accg[2][4], accu[2][4];
#pragma unroll
  for (int m = 0; m < 2; ++m)
#pragma unroll
    for (int n = 0; n < 4; ++n) {
      accg[m][n] = f32x4{0.f, 0.f, 0.f, 0.f};
      accu[m][n] = f32x4{0.f, 0.f, 0.f, 0.f};
    }

  const short* aptr[2];
#pragma unroll
  for (int i = 0; i < 2; ++i) {
    int r = (i * 4 + w) * 8 + (lane >> 3);
    int k8 = (lane & 7) ^ (r & 7);
    aptr[i] = A + (size_t)(row0 + r) * K + k8 * 8;
  }
  const short* bptr[8];
#pragma unroll
  for (int j = 0; j < 8; ++j) {
    int br = (j * 4 + w) * 8 + (lane >> 3);
    int k8 = (lane & 7) ^ (br & 7);
    bptr[j] = (br < 128 ? Wg + (size_t)(colg + br) * K
                        : Wu + (size_t)(colg + br - 128) * K) + k8 * 8;
  }

#define SAV(d, kt)                                                         \
  do {                                                                     \
    gload_lds16(aptr[0] + (kt), &lds[(d)*4096 + w * 512]);                 \
    gload_lds16(aptr[1] + (kt), &lds[(d)*4096 + 2048 + w * 512]);          \
  } while (0)
#define SBG(d, kt)                                                         \
  do {                                                                     \
    _Pragma("unroll") for (int j = 0; j < 4; ++j)                          \
        gload_lds16(bptr[j] + (kt), &lds[8192 + (d)*16384 + (j*4 + w)*512]);\
  } while (0)
#define SBU(d, kt)                                                         \
  do {                                                                     \
    _Pragma("unroll") for (int j = 4; j < 8; ++j)                          \
        gload_lds16(bptr[j] + (kt), &lds[8192 + (d)*16384 + (j*4 + w)*512]);\
  } while (0)
#define GATE(VN)                                              \
  asm volatile("s_waitcnt vmcnt(" #VN ")" ::: "memory");      \
  __builtin_amdgcn_s_barrier();                               \
  __builtin_amdgcn_sched_barrier(0);

  const int kg0 = (lane >> 4) ^ (lane & 7);
  const int kg1 = (4 + (lane >> 4)) ^ (lane & 7);
  const int aoff = (wr * 32 + (lane & 15)) * 64;
  const int bgoff = 8192 + (wc * 64 + (lane & 15)) * 64;
  const int buoff = bgoff + 8192;

#define READ_A(d)                                                              \
  _Pragma("unroll") for (int m = 0; m < 2; ++m) {                              \
    af[0][m] = *(const s16x8*)&lds[(d)*4096 + aoff + m * 1024 + kg0 * 8];      \
    af[1][m] = *(const s16x8*)&lds[(d)*4096 + aoff + m * 1024 + kg1 * 8];      \
  }
#define READ_BF(d, BOFF, BF)                                                   \
  _Pragma("unroll") for (int n = 0; n < 4; ++n) {                              \
    BF[0][n] = *(const s16x8*)&lds[(d)*16384 + (BOFF) + n * 1024 + kg0 * 8];   \
    BF[1][n] = *(const s16x8*)&lds[(d)*16384 + (BOFF) + n * 1024 + kg1 * 8];   \
  }
#define MMH(BF, g, ACC)                                                        \
  do {                                                                         \
    __builtin_amdgcn_s_setprio(1);                                             \
    _Pragma("unroll") for (int m = 0; m < 2; ++m)                              \
        _Pragma("unroll") for (int n = 0; n < 4; ++n)                          \
            ACC[m][n] = __builtin_amdgcn_mfma_f32_16x16x32_bf16(               \
                af[g][m], BF[g][n], ACC[m][n], 0, 0, 0);                       \
    __builtin_amdgcn_s_setprio(0);                                             \
  } while (0)

  SAV(0, 0); SBG(0, 0); SBU(0, 0);

  const int NT = K >> 6;
  for (int t = 0; t < NT - 1; ++t) {
    const int d = t & 1, d1 = d ^ 1;
    const int kn = (t + 1) * 64;
    s16x8 af[2][2], bg[2][4], bu[2][4];
    GATE(4);
    READ_A(d);
    READ_BF(d, bgoff, bg);
    MMH(bg, 0, accg);
    SAV(d1, kn);
    MMH(bg, 1, accg);
    SBG(d1, kn);
    GATE(6);
    READ_BF(d, buoff, bu);
    MMH(bu, 0, accu);
    SBU(d1, kn);
    MMH(bu, 1, accu);
  }
  {
    const int d = (NT - 1) & 1;
    s16x8 af[2][2], bg[2][4], bu[2][4];
    GATE(4);
    READ_A(d);
    READ_BF(d, bgoff, bg);
    MMH(bg, 0, accg);
    MMH(bg, 1, accg);
    GATE(0);
    READ_BF(d, buoff, bu);
    MMH(bu, 0, accu);
    MMH(bu, 1, accu);
  }
#undef SAV
#undef SBG
#undef SBU
#undef READ_A
#undef READ_BF
#undef MMH
#undef GATE

  const int li = lane >> 4, lc = lane & 15;
#pragma unroll
  for (int m = 0; m < 2; ++m) {
#pragma unroll
    for (int i = 0; i < 4; ++i) {
      int gr = row0 + wr * 32 + m * 16 + li * 4 + i;
      if (gr >= M) continue;
#pragma unroll
      for (int n = 0; n < 4; ++n) {
        int gc = colg + wc * 64 + n * 16 + lc;
        outp[(size_t)gr * 1536 + gc] = f2bf(silu_f(accg[m][n][i]) * accu[m][n][i]);
      }
    }
  }
}

// ====== fused GEMM + residual + RMS (BM=128, BN=512, single round) =========
template <int PROJ>
__global__ __launch_bounds__(512, 1) void gemm_norm(
    const short* __restrict__ A, const short* __restrict__ W,
    const float* __restrict__ bias, const short* __restrict__ residb,
    float* __restrict__ outf, short* __restrict__ hsb, int K)
{
  __shared__ short lds[81920];  // 160 KiB
  const int tid = threadIdx.x;
  const int wid = tid >> 6, lane = tid & 63;
  const int wr = wid >> 2, wc = wid & 3;
  const int row0 = blockIdx.x * 128;
  const int tid8 = tid * 8;

  f32x4 acc[4][8];
#pragma unroll
  for (int m = 0; m < 4; ++m)
#pragma unroll
    for (int n = 0; n < 8; ++n) acc[m][n] = f32x4{0.f, 0.f, 0.f, 0.f};

  const int srow = tid >> 3;
  const int k8s = (tid & 7) ^ (srow & 7);
  const short* aptr[2];
#pragma unroll
  for (int i = 0; i < 2; ++i)
    aptr[i] = A + (size_t)(row0 + i * 64 + srow) * K + k8s * 8;
  const short* bptr[8];
#pragma unroll
  for (int u = 0; u < 8; ++u)
    bptr[u] = W + (size_t)(u * 64 + srow) * K + k8s * 8;

#define STG(d, kt)                                                            \
  do {                                                                        \
    _Pragma("unroll") for (int i = 0; i < 2; ++i)                             \
        gload_lds16(aptr[i] + (kt), &lds[(d)*8192 + i*4096 + tid8]);          \
    _Pragma("unroll") for (int u = 0; u < 8; ++u)                             \
        gload_lds16(bptr[u] + (kt), &lds[16384 + (d)*32768 + u*4096 + tid8]); \
  } while (0)
#define GATEN(VN)                                             \
  asm volatile("s_waitcnt vmcnt(" #VN ")" ::: "memory");      \
  __builtin_amdgcn_s_barrier();                               \
  __builtin_amdgcn_sched_barrier(0);

  const int kg0 = (lane >> 4) ^ (lane & 7);
  const int kg1 = (4 + (lane >> 4)) ^ (lane & 7);
  const int arow = (wr * 64 + (lane & 15)) * 64;
  const int brow0 = (wc * 128 + (lane & 15)) * 64;

  STG(0, 0);
  const int NT = K >> 6;
  for (int t = 0; t < NT; ++t) {
    const int d = t & 1;
    if (t + 1 < NT) {
      STG(d ^ 1, (t + 1) * 64);
      GATEN(10);
    } else {
      GATEN(0);
    }
    s16x8 af0[4], af1[4];
#pragma unroll
    for (int m = 0; m < 4; ++m) {
      af0[m] = *(const s16x8*)&lds[d * 8192 + arow + m * 1024 + kg0 * 8];
      af1[m] = *(const s16x8*)&lds[d * 8192 + arow + m * 1024 + kg1 * 8];
    }
    __builtin_amdgcn_s_setprio(1);
#pragma unroll
    for (int n = 0; n < 8; ++n) {
      int bo = 16384 + d * 32768 + brow0 + n * 1024;
      s16x8 b0 = *(const s16x8*)&lds[bo + kg0 * 8];
      s16x8 b1 = *(const s16x8*)&lds[bo + kg1 * 8];
#pragma unroll
      for (int m = 0; m < 4; ++m)
        acc[m][n] = __builtin_amdgcn_mfma_f32_16x16x32_bf16(af0[m], b0, acc[m][n], 0, 0, 0);
#pragma unroll
      for (int m = 0; m < 4; ++m)
        acc[m][n] = __builtin_amdgcn_mfma_f32_16x16x32_bf16(af1[m], b1, acc[m][n], 0, 0, 0);
    }
    __builtin_amdgcn_s_setprio(0);
    __builtin_amdgcn_s_barrier();
  }
#undef STG
#undef GATEN

  const int li = lane >> 4, lc = lane & 15;
  float* fbuf = (float*)lds;
#pragma unroll
  for (int m = 0; m < 4; ++m) {
#pragma unroll
    for (int i = 0; i < 4; ++i) {
      int rowl = wr * 64 + m * 16 + li * 4 + i;
      int gr = row0 + rowl;
      float s = 0.f;
#pragma unroll
      for (int n = 0; n < 8; ++n) {
        int gc = wc * 128 + n * 16 + lc;
        float v = acc[m][n][i];
        if (PROJ) v += bias[gc] + bf2f(residb[(size_t)gr * 512 + gc]);
        else      v += outf[(size_t)gr * 512 + gc];
        acc[m][n][i] = v;
        s += v * v;
      }
      s += __shfl_xor(s, 1, 64);
      s += __shfl_xor(s, 2, 64);
      s += __shfl_xor(s, 4, 64);
      s += __shfl_xor(s, 8, 64);
      if (lc == 0) fbuf[rowl * 4 + wc] = s;
    }
  }
  __builtin_amdgcn_s_barrier();
#pragma unroll
  for (int m = 0; m < 4; ++m) {
#pragma unroll
    for (int i = 0; i < 4; ++i) {
      int rowl = wr * 64 + m * 16 + li * 4 + i;
      int gr = row0 + rowl;
      float tot = fbuf[rowl * 4] + fbuf[rowl * 4 + 1] + fbuf[rowl * 4 + 2] + fbuf[rowl * 4 + 3];
      float sc = rsqrtf(tot * (1.f / 512.f) + 1e-5f);
      size_t orow;
      if (PROJ) {
        int b = gr / 900, rem = gr % 900;
        int w = rem / 9, n_ = rem % 9;
        int wi = w / 10, wj = w % 10;
        int ii = n_ / 3, jj = n_ % 3;
        int gy = wi * 3 + ii + 1; if (gy >= 30) gy -= 30;
        int gx = wj * 3 + jj + 1; if (gx >= 30) gx -= 30;
        orow = ((size_t)b * 916 + 16 + gy * 30 + gx);
      } else {
        orow = (size_t)gr;
      }
#pragma unroll
      for (int n = 0; n < 8; ++n) {
        int gc = wc * 128 + n * 16 + lc;
        float v = acc[m][n][i] * sc;
        outf[orow * 512 + gc] = v;
        if (PROJ) hsb[orow * 512 + gc] = f2bf(v);
      }
    }
  }
}

// ================= 2-phase 128x128 GEMM (small prefix GEMMs) =====
template <int EPI>
__global__ __launch_bounds__(256) void gemm2(
    const short* __restrict__ A, const short* __restrict__ W,
    const short* __restrict__ Wu, const float* __restrict__ bias,
    void* __restrict__ outp, int M, int N, int K)
{
  __shared__ short As0[8192], Bs0[8192];
  __shared__ short As1[8192], Bs1[8192];
  const int tid = threadIdx.x;
  const int wave = tid >> 6, lane = tid & 63;
  const int nwg = gridDim.x * gridDim.y;
  const int orig = blockIdx.y * gridDim.x + blockIdx.x;
  const int wg = xcd_swizzle(orig, nwg);
  const int bx = wg % gridDim.x, by = wg / gridDim.x;
  const int row0 = by * 128;
  const int col0 = (EPI == EPI_GU) ? bx * 64 : bx * 128;
  const int wr = wave >> 1, wc = wave & 1;

  f32x4 acc[4][4];
#pragma unroll
  for (int m = 0; m < 4; ++m)
#pragma unroll
    for (int n = 0; n < 4; ++n) acc[m][n] = f32x4{0.f, 0.f, 0.f, 0.f};

  const short* aptr[4];
  const short* bptr[4];
  int ldst[4];
#pragma unroll
  for (int i = 0; i < 4; ++i) {
    int e = i * 2048 + tid * 8;
    int srow = e >> 6;
    int skg = ((e >> 3) & 7) ^ (srow & 7);
    aptr[i] = A + (size_t)(row0 + srow) * K + skg * 8;
    if (EPI == EPI_GU)
      bptr[i] = (srow < 64 ? W + (size_t)(col0 + srow) * K
                           : Wu + (size_t)(col0 + srow - 64) * K) + skg * 8;
    else
      bptr[i] = W + (size_t)(col0 + srow) * K + skg * 8;
    ldst[i] = i * 2048 + wave * 512;
  }

#define STAGE(AS, BS, KT)                                   \
  do {                                                      \
    _Pragma("unroll") for (int i = 0; i < 4; ++i)           \
        gload_lds16(aptr[i] + (KT), &AS[ldst[i]]);          \
    _Pragma("unroll") for (int i = 0; i < 4; ++i)           \
        gload_lds16(bptr[i] + (KT), &BS[ldst[i]]);          \
  } while (0)

#define COMPUTE(AS, BS)                                                        \
  do {                                                                         \
    _Pragma("unroll") for (int ks = 0; ks < 2; ++ks) {                         \
      s16x8 af[4], bfr[4];                                                     \
      _Pragma("unroll") for (int m = 0; m < 4; ++m) {                          \
        int row = wr * 64 + m * 16 + (lane & 15);                              \
        int kg = (ks * 4 + (lane >> 4)) ^ (row & 7);                           \
        af[m] = *(const s16x8*)&AS[row * 64 + kg * 8];                         \
      }                                                                        \
      _Pragma("unroll") for (int n = 0; n < 4; ++n) {                          \
        int brow = (EPI == EPI_GU)                                             \
                       ? ((n < 2 ? wc * 32 + n * 16                            \
                                 : 64 + wc * 32 + (n - 2) * 16) + (lane & 15)) \
                       : (wc * 64 + n * 16 + (lane & 15));                     \
        int kg = (ks * 4 + (lane >> 4)) ^ (brow & 7);                          \
        bfr[n] = *(const s16x8*)&BS[brow * 64 + kg * 8];                       \
      }                                                                        \
      _Pragma("unroll") for (int m = 0; m < 4; ++m)                            \
          _Pragma("unroll") for (int n = 0; n < 4; ++n)                        \
              acc[m][n] = __builtin_amdgcn_mfma_f32_16x16x32_bf16(             \
                  af[m], bfr[n], acc[m][n], 0, 0, 0);                          \
    }                                                                          \
  } while (0)

  STAGE(As0, Bs0, 0);
  sync_phase();
  for (int kt = 0; kt < K; kt += 128) {
    STAGE(As1, Bs1, kt + 64);
    COMPUTE(As0, Bs0);
    sync_phase();
    if (kt + 128 < K) STAGE(As0, Bs0, kt + 128);
    COMPUTE(As1, Bs1);
    if (kt + 128 < K) sync_phase();
  }
#undef STAGE
#undef COMPUTE

  const int lr = (lane >> 4) * 4, lc = lane & 15;
#pragma unroll
  for (int m = 0; m < 4; ++m) {
#pragma unroll
    for (int i = 0; i < 4; ++i) {
      int gr = row0 + wr * 64 + m * 16 + lr + i;
      if (EPI == EPI_GU) {
#pragma unroll
        for (int n = 0; n < 2; ++n) {
          int gc = col0 + wc * 32 + n * 16 + lc;
          float v = silu_f(acc[m][n][i]) * acc[m][n + 2][i];
          ((short*)outp)[(size_t)gr * N + gc] = f2bf(v);
        }
      } else {
#pragma unroll
        for (int n = 0; n < 4; ++n) {
          int gc = col0 + wc * 64 + n * 16 + lc;
          ((short*)outp)[(size_t)gr * N + gc] = f2bf(acc[m][n][i]);
        }
      }
    }
  }
}

// -------- fused weight conversion + prefix rows (one kernel) ---------------
__global__ __launch_bounds__(256) void cvt_all_kernel(
    const float* __restrict__ s_qkv, const float* __restrict__ s_proj,
    const float* __restrict__ s_gu, const float* __restrict__ s_down,
    const float* __restrict__ s_pgu, const float* __restrict__ s_pdown,
    const float* __restrict__ hs, short* __restrict__ dst,
    short* __restrict__ prefb) {
  int i = blockIdx.x * 256 + threadIdx.x;
  if (i >= 1507328) return;
  if (i >= 1441792) {
    int p = i - 1441792;
    int r = p >> 7, c4 = p & 127;
    int b = r >> 4, t = r & 15;
    f32x4 v = *(const f32x4*)(hs + ((size_t)b * 916 + t) * 512 + c4 * 4);
    s16x4 o;
#pragma unroll
    for (int e = 0; e < 4; ++e) o[e] = f2bf(v[e]);
    *(s16x4*)(prefb + (size_t)r * 512 + c4 * 4) = o;
    return;
  }
  const float* src;
  int base;
  if (i < 262144) {
    if (i < 196608) { src = s_qkv; base = 0; }
    else            { src = s_proj; base = 196608; }
  } else if (i < 851968) {
    if (i < 655360) { src = s_gu; base = 262144; }
    else            { src = s_down; base = 655360; }
  } else {
    if (i < 1245184) { src = s_pgu; base = 851968; }
    else             { src = s_pdown; base = 1245184; }
  }
  f32x4 v = *(const f32x4*)(src + (size_t)(i - base) * 4);
  s16x4 o;
#pragma unroll
  for (int e = 0; e < 4; ++e) o[e] = f2bf(v[e]);
  *(s16x4*)(dst + (size_t)i * 4) = o;
}

__global__ __launch_bounds__(512) void mean_kernel(const float* __restrict__ hs,
                                                   float* __restrict__ m) {
  int b = blockIdx.x, d = threadIdx.x;
  float s = 0.f;
#pragma unroll
  for (int t = 0; t < 16; ++t) s += hs[((size_t)b * 916 + t) * 512 + d];
  m[b * 512 + d] = s * (1.f / 16.f);
}

// grid = hs[:,16:] + mean -> bf16 window-partitioned xw
__global__ __launch_bounds__(256) void prep_kernel(const float* __restrict__ hs,
                                                   const float* __restrict__ m,
                                                   short* __restrict__ xw) {
  int idx = blockIdx.x * 256 + threadIdx.x;
  if (idx >= 32 * 900 * 128) return;
  int c4 = idx & 127;
  int row = idx >> 7;
  int b = row / 900, rem = row % 900;
  int gy = rem / 30, gx = rem % 30;
  f32x4 v = *(const f32x4*)(hs + ((size_t)b * 916 + 16 + rem) * 512 + c4 * 4);
  f32x4 mm = *(const f32x4*)(m + b * 512 + c4 * 4);
  v += mm;
  int ry = gy + 29; if (ry >= 30) ry -= 30;
  int rx = gx + 29; if (rx >= 30) rx -= 30;
  int wi = ry / 3, ii = ry % 3, wj = rx / 3, jj = rx % 3;
  size_t xrow = (size_t)((b * 100 + wi * 10 + wj) * 9 + ii * 3 + jj);
  s16x4 o;
#pragma unroll
  for (int e = 0; e < 4; ++e) o[e] = f2bf(v[e]);
  *(s16x4*)(xw + xrow * 512 + c4 * 4) = o;
}

// ---------------- windowed attention (9 tokens, 8 heads per window) ----------
__global__ __launch_bounds__(256) void attn_kernel(const short* __restrict__ qkv,
                                                   const float* __restrict__ rel_bias,
                                                   short* __restrict__ outp) {
  __shared__ short sq[9 * 512];
  __shared__ short sk[9 * 512];
  __shared__ short sv[9 * 512];
  __shared__ float sS[648];
  const int wlin = blockIdx.x;
  const int w = wlin % 100;
  const int wi = w / 10, wj = w % 10;
  const int tid = threadIdx.x;
  const short* base = qkv + (size_t)wlin * 9 * 1536;
  for (int idx = tid; idx < 1728; idx += 256) {
    int n = idx / 192, c8 = idx % 192;
    s16x8 v = *(const s16x8*)(base + (size_t)n * 1536 + c8 * 8);
    int which = c8 >> 6;
    short* dst = (which == 0) ? sq : (which == 1) ? sk : sv;
    *(s16x8*)(dst + n * 512 + (c8 & 63) * 8) = v;
  }
  __syncthreads();
  for (int idx = tid; idx < 648; idx += 256) {
    int h = idx / 81, r = idx % 81, i = r / 9, j = r % 9;
    const short* qp = sq + i * 512 + h * 64;
    const short* kp = sk + j * 512 + h * 64;
    float dot = 0.f;
#pragma unroll
    for (int c = 0; c < 8; ++c) {
      s16x8 qv = *(const s16x8*)(qp + c * 8);
      s16x8 kv = *(const s16x8*)(kp + c * 8);
#pragma unroll
      for (int e = 0; e < 8; ++e) dot += bf2f(qv[e]) * bf2f(kv[e]);
    }
    float s = dot * 0.125f;
    int ia = i / 3, ja = i % 3, ib = j / 3, jb = j % 3;
    s += rel_bias[(5 * (ia - ib + 2) + (ja - jb + 2)) * 8 + h];
    int ra = wi * 3 + ia, ca = wj * 3 + ja, rb = wi * 3 + ib, cb = wj * 3 + jb;
    int rga = (ra < 27) ? 0 : (ra < 29) ? 1 : 2;
    int cga = (ca < 27) ? 0 : (ca < 29) ? 1 : 2;
    int rgb = (rb < 27) ? 0 : (rb < 29) ? 1 : 2;
    int cgb = (cb < 27) ? 0 : (cb < 29) ? 1 : 2;
    if (rga * 3 + cga != rgb * 3 + cgb) s -= 100.f;
    sS[idx] = s;
  }
  __syncthreads();
  if (tid < 72) {
    float* row = sS + tid * 9;
    float mx = row[0];
#pragma unroll
    for (int j = 1; j < 9; ++j) mx = fmaxf(mx, row[j]);
    float e[9], sum = 0.f;
#pragma unroll
    for (int j = 0; j < 9; ++j) { e[j] = __expf(row[j] - mx); sum += e[j]; }
    float inv = 1.f / sum;
#pragma unroll
    for (int j = 0; j < 9; ++j) row[j] = e[j] * inv;
  }
  __syncthreads();
  for (int idx = tid; idx < 576; idx += 256) {
    int h = idx / 72, r = idx % 72, i = r / 8, d8 = r % 8;
    const float* p = sS + (h * 9 + i) * 9;
    float a[8] = {0, 0, 0, 0, 0, 0, 0, 0};
#pragma unroll
    for (int j = 0; j < 9; ++j) {
      float pj = p[j];
      s16x8 vv = *(const s16x8*)(sv + j * 512 + h * 64 + d8 * 8);
#pragma unroll
      for (int e = 0; e < 8; ++e) a[e] += pj * bf2f(vv[e]);
    }
    s16x8 o;
#pragma unroll
    for (int e = 0; e < 8; ++e) o[e] = f2bf(a[e]);
    *(s16x8*)(outp + ((size_t)wlin * 9 + i) * 512 + h * 64 + d8 * 8) = o;
  }
}

// ---------------- prefix add + RMS norm (4 rows per block) -----------------
__global__ __launch_bounds__(256) void prefix_addnorm_kernel(const float* __restrict__ hs,
                                                             const short* __restrict__ pd,
                                                             float* __restrict__ out,
                                                             short* __restrict__ hsb) {
  int r = blockIdx.x * 4 + (threadIdx.x >> 6);
  int lane = threadIdx.x & 63;
  int b = r >> 4, t = r & 15;
  size_t orow = ((size_t)b * 916 + t) * 512 + lane * 8;
  f32x4 a0 = *(const f32x4*)(hs + orow);
  f32x4 a1 = *(const f32x4*)(hs + orow + 4);
  s16x8 d8 = *(const s16x8*)(pd + (size_t)r * 512 + lane * 8);
  float x[8];
  float ss = 0.f;
#pragma unroll
  for (int e = 0; e < 8; ++e) {
    x[e] = (e < 4 ? a0[e] : a1[e - 4]) + bf2f(d8[e]);
    ss += x[e] * x[e];
  }
  ss = wave_allsum(ss);
  float sc = rsqrtf(ss * (1.f / 512.f) + 1e-5f);
  s16x8 o;
#pragma unroll
  for (int e = 0; e < 8; ++e) {
    x[e] *= sc;
    o[e] = f2bf(x[e]);
  }
  *(f32x4*)(out + orow) = f32x4{x[0], x[1], x[2], x[3]};
  *(f32x4*)(out + orow + 4) = f32x4{x[4], x[5], x[6], x[7]};
  *(s16x8*)(hsb + orow) = o;
}

// ---------------- workspace layout (bytes; liveness-overlaid) ----------------
static constexpr size_t OFF_WQKV   = 0;
static constexpr size_t OFF_WPROJ  = 1572864;
static constexpr size_t OFF_WGU    = 2097152;
static constexpr size_t OFF_WDOWN  = 5242880;
static constexpr size_t OFF_WPGU   = 6815744;
static constexpr size_t OFF_WPDOWN = 9961472;   // weights end 11534336
static constexpr size_t OFF_MEAN   = 11534336;
static constexpr size_t OFF_PREFB  = 11599872;
static constexpr size_t OFF_PINTER = 13697024;
static constexpr size_t OFF_PDOUT  = 15269888;  // end 15794176
static constexpr size_t OFF_XW     = 16777216;  // 28800*512*2 -> 46268416 (live 2..5)
static constexpr size_t OFF_QKV    = 46399488;  // 28800*1536*2 -> 134873088 (live 3..4)
static constexpr size_t OFF_ATTNO  = 134873088; // 28800*512*2 -> 164364288 (live 4..5)
static constexpr size_t OFF_INTER  = OFF_XW;    // 29312*1536*2 -> 106823680 (live 7..8)
static constexpr size_t OFF_HSB    = 164364288; // 29312*512*2 -> 194379776 (live 5..7)

extern "C" void kernel_launch(void* const* d_in, const int* in_sizes, int n_in,
                              void* d_out, int out_size, void* d_ws, size_t ws_size,
                              hipStream_t stream) {
  const float* hs      = (const float*)d_in[0];
  const float* qkv_w   = (const float*)d_in[1];
  const float* qkv_b   = (const float*)d_in[2];
  const float* proj_w  = (const float*)d_in[3];
  const float* proj_b  = (const float*)d_in[4];
  const float* rel_b   = (const float*)d_in[5];
  const float* gu_w    = (const float*)d_in[6];
  const float* down_w  = (const float*)d_in[7];
  const float* pgu_w   = (const float*)d_in[8];
  const float* pdown_w = (const float*)d_in[9];

  char* ws = (char*)d_ws;
  short* Wqkv   = (short*)(ws + OFF_WQKV);
  short* Wproj  = (short*)(ws + OFF_WPROJ);
  short* Wgu    = (short*)(ws + OFF_WGU);
  short* Wdown  = (short*)(ws + OFF_WDOWN);
  short* Wpgu   = (short*)(ws + OFF_WPGU);
  short* Wpdown = (short*)(ws + OFF_WPDOWN);
  float* meanb  = (float*)(ws + OFF_MEAN);
  short* prefb  = (short*)(ws + OFF_PREFB);
  short* pinter = (short*)(ws + OFF_PINTER);
  short* pdout  = (short*)(ws + OFF_PDOUT);
  short* xw     = (short*)(ws + OFF_XW);
  short* qkvb   = (short*)(ws + OFF_QKV);
  short* attno  = (short*)(ws + OFF_ATTNO);
  short* interb = (short*)(ws + OFF_INTER);
  short* hsb    = (short*)(ws + OFF_HSB);
  float* outf   = (float*)d_out;

  // 1. all weights fp32 -> bf16 + prefix rows (one kernel)
  cvt_all_kernel<<<5888, 256, 0, stream>>>(qkv_w, proj_w, gu_w, down_w,
                                           pgu_w, pdown_w, hs, (short*)ws, prefb);

  // 2. prefix mean -> windowed bf16 input
  mean_kernel<<<32, 512, 0, stream>>>(hs, meanb);
  prep_kernel<<<14400, 256, 0, stream>>>(hs, meanb, xw);

  // 3. QKV projection (M=28800, N=1536, K=512)
  gemm8<EPI_BIAS_BF16><<<dim3(6, 113), 512, 0, stream>>>(
      xw, Wqkv, qkv_b, qkvb, 28800, 1536, 512);
  // 4. windowed attention
  attn_kernel<<<3200, 256, 0, stream>>>(qkvb, rel_b, attno);

  // 5. fused proj + bias + residual(xw) + RMS + roll-scatter
  gemm_norm<1><<<225, 512, 0, stream>>>(attno, Wproj, proj_b, xw, outf, hsb, 512);

  // 6. prefix branch: swiglu + down + rms (fills prefix rows of outf/hsb)
  gemm2<EPI_GU><<<dim3(24, 4), 256, 0, stream>>>(
      prefb, Wpgu, Wpgu + 1536 * 512, nullptr, pinter, 512, 1536, 512);
  gemm2<EPI_BF16><<<dim3(4, 4), 256, 0, stream>>>(
      pinter, Wpdown, nullptr, nullptr, pdout, 512, 512, 1536);
  prefix_addnorm_kernel<<<128, 256, 0, stream>>>(hs, pdout, outf, hsb);

  // 7. full-sequence fused swiglu (M=29312, v4 16x16, 2 blocks/CU)
  gemm8gu<<<dim3(12, 458), 256, 0, stream>>>(
      hsb, Wgu, Wgu + 1536 * 512, interb, 29312, 512);
  // 8. fused down + residual(outf) + RMS in place (final output)
  gemm_norm<0><<<229, 512, 0, stream>>>(interb, Wdown, nullptr, nullptr, outf,
                                        nullptr, 1536);

  (void)in_sizes; (void)n_in; (void)out_size; (void)ws_size;
}